// Round 9
// baseline (286.280 us; speedup 1.0000x reference)
//
#include <hip/hip_runtime.h>
#include <hip/hip_cooperative_groups.h>
namespace cg = cooperative_groups;

#define N_TOK 4096
#define C_IN 256
#define CI_ 128

typedef unsigned short u16;
typedef unsigned int   u32;
typedef __attribute__((ext_vector_type(8))) short bf16x8;
typedef __attribute__((ext_vector_type(4))) float f32x4;

// ---- bf16 helpers ----
__device__ __forceinline__ float lo16f(u32 u){ union{u32 i; float f;} c; c.i = u << 16; return c.f; }
__device__ __forceinline__ float hi16f(u32 u){ union{u32 i; float f;} c; c.i = u & 0xffff0000u; return c.f; }
__device__ __forceinline__ void bf8f(const uint4 u, float* f){
    f[0]=lo16f(u.x); f[1]=hi16f(u.x); f[2]=lo16f(u.y); f[3]=hi16f(u.y);
    f[4]=lo16f(u.z); f[5]=hi16f(u.z); f[6]=lo16f(u.w); f[7]=hi16f(u.w);
}
__device__ __forceinline__ float bf1f(u16 v){ union{u32 i; float f;} c; c.i = ((u32)v)<<16; return c.f; }
__device__ __forceinline__ u16 f2bf(float f){
    union{float f; u32 i;} c; c.f = f;
    u32 i = c.i;
    u32 r = (i + 0x7fffu + ((i >> 16) & 1u)) >> 16;   // RNE
    return (u16)r;
}
__device__ __forceinline__ u32 packbf(float a, float b){
    return (u32)f2bf(a) | ((u32)f2bf(b) << 16);
}

__device__ __forceinline__ void load8(const void* base, size_t idx, int flag, float* f){
    if (flag) {
        const float* p = (const float*)base + idx;
        *(float4*)&f[0] = *(const float4*)p;
        *(float4*)&f[4] = *(const float4*)(p + 4);
    } else {
        uint4 u = *(const uint4*)((const u16*)base + idx);
        bf8f(u, f);
    }
}
__device__ __forceinline__ void load4(const void* base, size_t idx, int flag, float* f){
    if (flag) {
        float4 v = *(const float4*)((const float*)base + idx);
        f[0]=v.x; f[1]=v.y; f[2]=v.z; f[3]=v.w;
    } else {
        uint2 u = *(const uint2*)((const u16*)base + idx);
        f[0]=lo16f(u.x); f[1]=hi16f(u.x); f[2]=lo16f(u.y); f[3]=hi16f(u.y);
    }
}

// async global->LDS DMA, 16B per lane, dest = wave-uniform base + lane*16
__device__ __forceinline__ void dma16(const u16* g, char* l){
    __builtin_amdgcn_global_load_lds(
        (const __attribute__((address_space(1))) u32*)g,
        (__attribute__((address_space(3))) u32*)l, 16, 0, 0);
}

// =====================================================================
// Kernel 1: prep = param canonicalize (549 blocks) + x transpose (1024).
// dtype flag detected inline per block (no cross-block dependency).
// =====================================================================
__global__ __launch_bounds__(256) void prep_kernel(
    const void* x, const void* wg, const void* wt, const void* wp, const void* wo,
    const void* bg, const void* bt, const void* bp, const void* bo,
    const void* gm, const void* bt2,
    int* __restrict__ flagp, float* __restrict__ canon, u16* __restrict__ canon_bf,
    float* __restrict__ stats, u16* __restrict__ xbfT)
{
    __shared__ int sflag;
    __shared__ u16 t[64][72];
    const int tid = threadIdx.x;
    if (tid < 64) {
        int cnt = 0;
        const u16* wgp = (const u16*)wg;
        for (int i = tid; i < 256; i += 64) {
            u16 v = wgp[2 * i];
            if (((v >> 7) & 0xFF) >= 128) cnt++;
        }
        #pragma unroll
        for (int off = 32; off; off >>= 1) cnt += __shfl_down(cnt, off);
        if (tid == 0) sflag = (cnt >= 8) ? 1 : 0;
    }
    __syncthreads();
    const int flag = sflag;
    const int bid = blockIdx.x;

    if (bid < 549) {
        if (bid == 0 && tid == 0) *flagp = flag;
        int idx = bid * 256 + tid;
        if (idx >= 132224) {
            int j = idx - 132224;
            if (j < 4096) stats[j] = 0.f;
            return;
        }
        const void* src; int loc;
        if      (idx < 32768)  { src = wg;  loc = idx; }
        else if (idx < 65536)  { src = wt;  loc = idx - 32768; }
        else if (idx < 98304)  { src = wp;  loc = idx - 65536; }
        else if (idx < 131072) { src = wo;  loc = idx - 98304; }
        else if (idx < 131200) { src = bg;  loc = idx - 131072; }
        else if (idx < 131328) { src = bt;  loc = idx - 131200; }
        else if (idx < 131456) { src = bp;  loc = idx - 131328; }
        else if (idx < 131712) { src = bo;  loc = idx - 131456; }
        else if (idx < 131968) { src = gm;  loc = idx - 131712; }
        else                   { src = bt2; loc = idx - 131968; }
        float v = flag ? ((const float*)src)[loc] : bf1f(((const u16*)src)[loc]);
        canon[idx] = v;
        if (idx < 131072) canon_bf[idx] = f2bf(v);
    } else {
        // xpose: x [b][k][n] -> xbfT [b][n][k] bf16
        int tb = bid - 549;
        int nb = tb & 63, kb = (tb >> 6) & 3, b = tb >> 8;
        const int k0 = kb * 64, n0 = nb * 64;
        const size_t xb = (size_t)b * C_IN * N_TOK;
        {
            int kk = tid >> 4, n4 = (tid & 15) * 4;
            #pragma unroll
            for (int i = 0; i < 4; ++i) {
                float f[4];
                load4(x, xb + (size_t)(k0 + kk + i * 16) * N_TOK + n0 + n4, flag, f);
                #pragma unroll
                for (int j = 0; j < 4; ++j) t[n4 + j][kk + i * 16] = f2bf(f[j]);
            }
        }
        __syncthreads();
        {
            int kq = tid & 3, n = tid >> 2;
            u16* dst = &xbfT[((size_t)b * N_TOK + n0 + n) * C_IN + k0 + kq * 16];
            *(uint4*)(dst + 0) = *(const uint4*)&t[n][kq * 16];
            *(uint4*)(dst + 8) = *(const uint4*)&t[n][kq * 16 + 8];
        }
    }
}

// =====================================================================
// Kernel 2 (cooperative, 256 blocks x 512 thr, 1 block/CU):
//   Phase A: MFMA proj (R7 body)      -> gbuf/tbufT/pbufT
//   grid.sync
//   Phase B: R7-verbatim attn + fused outproj + bucketed stats -> wyb
//   grid.sync
//   Phase C: stats finalize + BN + residual -> out
// =====================================================================
#define PB2   131072
#define MST2  147456
#define LST2  147712
#define SMEM2 147968

__global__ __launch_bounds__(512) void mega_kernel(
    const u16* __restrict__ xbfT, const float* __restrict__ canon,
    const u16* __restrict__ wbf,
    u16* __restrict__ gbuf, u16* __restrict__ tbufT, u16* __restrict__ pbufT,
    u16* __restrict__ wyb, float* __restrict__ stats,
    const void* __restrict__ x, const int* __restrict__ flagp,
    void* __restrict__ outv)
{
    __shared__ __align__(16) char smem[SMEM2];
    cg::grid_group grid = cg::this_grid();
    const int bx  = blockIdx.x;
    const int b   = blockIdx.y;
    const int tid = threadIdx.x;
    const int w    = tid >> 6;
    const int lane = tid & 63;
    const int col  = lane & 15;
    const int quad = lane >> 4;
    const size_t bN = (size_t)b * N_TOK;
    const size_t bC = (size_t)b * CI_;

    // ================= Phase A: proj =================
    {
        u16* plds = (u16*)smem;
        const int n0 = bx * 64;
        const int rw = w * 48;
        f32x4 acc[3][4];
        #pragma unroll
        for (int i = 0; i < 3; ++i)
            #pragma unroll
            for (int j = 0; j < 4; ++j) acc[i][j] = (f32x4){0.f,0.f,0.f,0.f};

        #pragma unroll
        for (int kc = 0; kc < 8; ++kc) {
            bf16x8 bfr[4];
            #pragma unroll
            for (int nf = 0; nf < 4; ++nf)
                bfr[nf] = *(const bf16x8*)&xbfT[(bN + n0 + nf * 16 + col) * C_IN + kc * 32 + quad * 8];
            #pragma unroll
            for (int rs = 0; rs < 3; ++rs) {
                bf16x8 afr = *(const bf16x8*)&wbf[(size_t)(rw + rs * 16 + col) * 256 + kc * 32 + quad * 8];
                #pragma unroll
                for (int nf = 0; nf < 4; ++nf)
                    acc[rs][nf] = __builtin_amdgcn_mfma_f32_16x16x32_bf16(afr, bfr[nf], acc[rs][nf], 0, 0, 0);
            }
        }
        #pragma unroll
        for (int rs = 0; rs < 3; ++rs) {
            int r0 = rw + rs * 16 + quad * 4;
            float b0 = canon[131072 + r0 + 0];
            float b1 = canon[131072 + r0 + 1];
            float b2 = canon[131072 + r0 + 2];
            float b3 = canon[131072 + r0 + 3];
            #pragma unroll
            for (int nf = 0; nf < 4; ++nf) {
                int n = nf * 16 + col;
                uint2 pv;
                pv.x = packbf(acc[rs][nf][0] + b0, acc[rs][nf][1] + b1);
                pv.y = packbf(acc[rs][nf][2] + b2, acc[rs][nf][3] + b3);
                *(uint2*)&plds[n * 400 + r0] = pv;
            }
        }
        __syncthreads();
        {
            int r = tid & 127, nq = tid >> 7;
            u16 tmp[16];
            #pragma unroll
            for (int j = 0; j < 16; ++j) tmp[j] = plds[(nq * 16 + j) * 400 + r];
            u16* dst = &gbuf[(bC + r) * N_TOK + n0 + nq * 16];
            *(uint4*)(dst + 0) = *(uint4*)&tmp[0];
            *(uint4*)(dst + 8) = *(uint4*)&tmp[8];
        }
        {
            int n = tid & 63, part = tid >> 6;
            const u16* src = (part < 4) ? &plds[n * 400 + 128 + part * 32]
                                        : &plds[n * 400 + 256 + (part - 4) * 32];
            u16* dst = (part < 4) ? &tbufT[(bN + n0 + n) * CI_ + part * 32]
                                  : &pbufT[(bN + n0 + n) * CI_ + (part - 4) * 32];
            #pragma unroll
            for (int v = 0; v < 4; ++v) *(uint4*)(dst + v * 8) = *(const uint4*)(src + v * 8);
        }
    }
    grid.sync();

    // ================= Phase B: attn (R7-verbatim) =================
    {
        const int q0 = bx * 64;
        const int wq = w & 3;
        const int ms = w >> 2;
        const int qw = wq * 16;

        bf16x8 thf[4];
        {
            const u16* tb = tbufT + (bN + q0 + qw + col) * CI_;
            #pragma unroll
            for (int kc = 0; kc < 4; ++kc)
                thf[kc] = *(const bf16x8*)(tb + kc * 32 + quad * 8);
        }

        const u16* sbp[8];
        int ldso[8];
        int sstep;
        if (w < 4) {
            int r = lane >> 4, cp = lane & 15;
            sstep = 128 * CI_;
            #pragma unroll
            for (int j = 0; j < 8; ++j) {
                int seg = w * 8 + j, p = seg >> 4, m0 = (seg & 15) * 4;
                int m = m0 + r, h = cp ^ (m & 15);
                sbp[j] = pbufT + (bN + p * 64 + m) * CI_ + h * 8;
                ldso[j] = p * 16384 + m0 * 256;
            }
        } else {
            int r = lane >> 3, cp = lane & 7;
            sstep = 128;
            #pragma unroll
            for (int j = 0; j < 8; ++j) {
                int seg = (w - 4) * 8 + j, p = seg >> 4, c0 = (seg & 15) * 8;
                int c = c0 + r, h = cp ^ (c & 7);
                sbp[j] = gbuf + (bC + c) * N_TOK + p * 64 + h * 8;
                ldso[j] = 65536 + p * 16384 + c0 * 128;
            }
        }

        f32x4 yacc[8];
        #pragma unroll
        for (int i = 0; i < 8; ++i) yacc[i] = (f32x4){0.f, 0.f, 0.f, 0.f};
        float m_st = -3.0e38f, l_st = 0.f;

        #pragma unroll
        for (int j = 0; j < 8; ++j) dma16(sbp[j], smem + ldso[j]);

        for (int s = 0; s < 32; ++s) {
            const int bb = (s & 1) << 15;
            __asm volatile("s_waitcnt lgkmcnt(0)" ::: "memory");
            __asm volatile("s_barrier" ::: "memory");
            if (s < 31) {
                const int nb = ((s + 1) & 1) << 15;
                const size_t so = (size_t)(s + 1) * sstep;
                #pragma unroll
                for (int j = 0; j < 8; ++j) dma16(sbp[j] + so, smem + nb + ldso[j]);
                __asm volatile("s_waitcnt vmcnt(8)" ::: "memory");
            } else {
                __asm volatile("s_waitcnt vmcnt(0)" ::: "memory");
            }
            __asm volatile("s_barrier" ::: "memory");

            f32x4 sacc[4];
            #pragma unroll
            for (int i = 0; i < 4; ++i) sacc[i] = (f32x4){0.f, 0.f, 0.f, 0.f};
            #pragma unroll
            for (int kc = 0; kc < 4; ++kc) {
                #pragma unroll
                for (int msub = 0; msub < 4; ++msub) {
                    int m = msub * 16 + col;
                    int h = kc * 4 + quad;
                    bf16x8 af = *(const bf16x8*)(smem + bb + ms * 16384 + m * 256 + ((h ^ (m & 15)) << 4));
                    sacc[msub] = __builtin_amdgcn_mfma_f32_16x16x32_bf16(af, thf[kc], sacc[msub], 0, 0, 0);
                }
            }

            float tmax = sacc[0][0];
            #pragma unroll
            for (int i = 0; i < 4; ++i)
                #pragma unroll
                for (int r = 0; r < 4; ++r) tmax = fmaxf(tmax, sacc[i][r]);
            tmax = fmaxf(tmax, __shfl_xor(tmax, 16));
            tmax = fmaxf(tmax, __shfl_xor(tmax, 32));
            float m_new = fmaxf(m_st, tmax);
            float p16[16], ps = 0.f;
            #pragma unroll
            for (int i = 0; i < 4; ++i)
                #pragma unroll
                for (int r = 0; r < 4; ++r) {
                    float pv = __expf(sacc[i][r] - m_new);
                    p16[i * 4 + r] = pv;
                    ps += pv;
                }
            ps += __shfl_xor(ps, 16);
            ps += __shfl_xor(ps, 32);
            float alpha = __expf(m_st - m_new);
            l_st = l_st * alpha + ps;
            m_st = m_new;
            #pragma unroll
            for (int i = 0; i < 8; ++i) {
                yacc[i][0] *= alpha; yacc[i][1] *= alpha;
                yacc[i][2] *= alpha; yacc[i][3] *= alpha;
            }

            {
                char* pb = smem + PB2 + w * 2048 + col * 128;
                #pragma unroll
                for (int msub = 0; msub < 4; ++msub) {
                    #pragma unroll
                    for (int pr = 0; pr < 2; ++pr) {
                        u32 d = packbf(p16[msub * 4 + pr * 2], p16[msub * 4 + pr * 2 + 1]);
                        int h = msub * 2 + (quad >> 1);
                        *(u32*)(pb + ((h ^ (col & 7)) << 4) + (quad & 1) * 8 + pr * 4) = d;
                    }
                }
            }
            __asm volatile("s_waitcnt lgkmcnt(0)" ::: "memory");

            bf16x8 pf[2];
            #pragma unroll
            for (int km = 0; km < 2; ++km) {
                int h = km * 4 + quad;
                pf[km] = *(const bf16x8*)(smem + PB2 + w * 2048 + col * 128 + ((h ^ (col & 7)) << 4));
            }
            #pragma unroll
            for (int csub = 0; csub < 8; ++csub) {
                #pragma unroll
                for (int km = 0; km < 2; ++km) {
                    int c = csub * 16 + col;
                    int h = km * 4 + quad;
                    bf16x8 gf = *(const bf16x8*)(smem + 65536 + bb + ms * 16384 + c * 128 + ((h ^ (c & 7)) << 4));
                    yacc[csub] = __builtin_amdgcn_mfma_f32_16x16x32_bf16(gf, pf[km], yacc[csub], 0, 0, 0);
                }
            }
        }

        __syncthreads();
        if (ms == 1) {
            char* mb = smem + wq * 8192 + col * 512;
            #pragma unroll
            for (int csub = 0; csub < 8; ++csub)
                *(f32x4*)(mb + (((csub * 4 + quad) ^ col) << 4)) = yacc[csub];
            if (quad == 0) {
                *(float*)(smem + MST2 + (wq * 16 + col) * 4) = m_st;
                *(float*)(smem + LST2 + (wq * 16 + col) * 4) = l_st;
            }
        }
        __syncthreads();
        if (ms == 0) {
            float m1 = *(const float*)(smem + MST2 + (wq * 16 + col) * 4);
            float l1 = *(const float*)(smem + LST2 + (wq * 16 + col) * 4);
            float M  = fmaxf(m_st, m1);
            float a0 = __expf(m_st - M), a1 = __expf(m1 - M);
            float li = 1.f / (l_st * a0 + l1 * a1);
            float s0 = a0 * li, s1 = a1 * li;
            const char* mb = smem + wq * 8192 + col * 512;
            const int q = qw + col;
            #pragma unroll
            for (int csub = 0; csub < 8; ++csub) {
                f32x4 y1 = *(const f32x4*)(mb + (((csub * 4 + quad) ^ col) << 4));
                uint2 pv;
                pv.x = packbf(yacc[csub][0] * s0 + y1[0] * s1, yacc[csub][1] * s0 + y1[1] * s1);
                pv.y = packbf(yacc[csub][2] * s0 + y1[2] * s1, yacc[csub][3] * s0 + y1[3] * s1);
                int chunk = csub * 2 + (quad >> 1);
                *(uint2*)(smem + 32768 + q * 256 + ((chunk ^ (q & 15)) << 4) + (quad & 1) * 8) = pv;
            }
        }
        __syncthreads();

        // fused outproj
        const u16* wo = wbf + 98304;
        f32x4 oacc[2][4];
        #pragma unroll
        for (int i = 0; i < 2; ++i)
            #pragma unroll
            for (int j = 0; j < 4; ++j) oacc[i][j] = (f32x4){0.f,0.f,0.f,0.f};
        #pragma unroll
        for (int kc = 0; kc < 4; ++kc) {
            bf16x8 bqf[4];
            #pragma unroll
            for (int qf = 0; qf < 4; ++qf) {
                int q = qf * 16 + col;
                int h = kc * 4 + quad;
                bqf[qf] = *(const bf16x8*)(smem + 32768 + q * 256 + ((h ^ (q & 15)) << 4));
            }
            #pragma unroll
            for (int os = 0; os < 2; ++os) {
                bf16x8 afr = *(const bf16x8*)&wo[(size_t)(w * 32 + os * 16 + col) * CI_ + kc * 32 + quad * 8];
                #pragma unroll
                for (int qf = 0; qf < 4; ++qf)
                    oacc[os][qf] = __builtin_amdgcn_mfma_f32_16x16x32_bf16(afr, bqf[qf], oacc[os][qf], 0, 0, 0);
            }
        }
        const int bucket = (bx + b) & 7;
        float* sbk = stats + bucket * 512;
        #pragma unroll
        for (int os = 0; os < 2; ++os) {
            int ob = w * 32 + os * 16 + quad * 4;
            #pragma unroll
            for (int i = 0; i < 4; ++i) {
                float bb2 = canon[131456 + ob + i];
                float s1 = 0.f, s2 = 0.f;
                u16* dst = &wyb[((size_t)b * C_IN + ob + i) * N_TOK + q0 + col];
                #pragma unroll
                for (int qf = 0; qf < 4; ++qf) {
                    float v = oacc[os][qf][i] + bb2;
                    dst[qf * 16] = f2bf(v);
                    s1 += v;
                    s2 += v * v;
                }
                #pragma unroll
                for (int off = 8; off; off >>= 1) {
                    s1 += __shfl_xor(s1, off);
                    s2 += __shfl_xor(s2, off);
                }
                if (col == 0) {
                    atomicAdd(&sbk[ob + i], s1);
                    atomicAdd(&sbk[256 + ob + i], s2);
                }
            }
        }
    }
    grid.sync();

    // ================= Phase C: BN + residual =================
    {
        const int flag = *flagp;
        const int o = bx * 4 + (tid >> 7);          // 4 channels per block
        const int l128 = tid & 127;
        float sum1 = 0.f, sum2 = 0.f;
        #pragma unroll
        for (int k = 0; k < 8; ++k) {
            sum1 += stats[k * 512 + o];
            sum2 += stats[k * 512 + 256 + o];
        }
        float mean = sum1 * (1.f / 16384.f);
        float var  = sum2 * (1.f / 16384.f) - mean * mean;
        float r = rsqrtf(var + 1e-5f);
        float gmv = canon[131712 + o], btv = canon[131968 + o];
        const size_t rowb = ((size_t)b * C_IN + o) * N_TOK;
        #pragma unroll
        for (int j = 0; j < 4; ++j) {
            size_t base = rowb + (size_t)l128 * 32 + j * 8;
            uint4 wu = *(const uint4*)&wyb[base];
            float wv[8]; bf8f(wu, wv);
            float xf[8]; load8(x, base, flag, xf);
            float ov[8];
            #pragma unroll
            for (int i = 0; i < 8; ++i)
                ov[i] = (wv[i] - mean) * r * gmv + btv + xf[i];
            if (flag) {
                float* op = (float*)outv + base;
                *(float4*)op       = *(float4*)&ov[0];
                *(float4*)(op + 4) = *(float4*)&ov[4];
            } else {
                uint4 res;
                res.x = packbf(ov[0], ov[1]);
                res.y = packbf(ov[2], ov[3]);
                res.z = packbf(ov[4], ov[5]);
                res.w = packbf(ov[6], ov[7]);
                *(uint4*)((u16*)outv + base) = res;
            }
        }
    }
}

extern "C" void kernel_launch(void* const* d_in, const int* in_sizes, int n_in,
                              void* d_out, int out_size, void* d_ws, size_t ws_size,
                              hipStream_t stream)
{
    const void* x   = d_in[0];
    const void* w_g = d_in[1];
    const void* b_g = d_in[2];
    const void* w_t = d_in[3];
    const void* b_t = d_in[4];
    const void* w_p = d_in[5];
    const void* b_p = d_in[6];
    const void* w_o = d_in[7];
    const void* b_o = d_in[8];
    const void* gm  = d_in[9];
    const void* bt  = d_in[10];

    char* base = (char*)d_ws;
    float* canon    = (float*)base;                    // 132224 f32
    u16*   canon_bf = (u16*)(base + 528896);           // 131072 u16
    int*   flagp    = (int*)(base + 791040);
    float* stats    = (float*)(base + 791296);         // 8 buckets x 512 f32
    u16*   gbuf     = (u16*)(base + 1048576);          // 4 MB bf16 [b][c][n]
    u16*   tbufT    = (u16*)(base + 5242880);          // 4 MB bf16 [b][n][c]
    u16*   pbufT    = (u16*)(base + 9437184);          // 4 MB bf16 [b][n][c]
    u16*   wyb      = (u16*)(base + 13631488);         // 8 MB bf16 [b][o][n]
    u16*   xbfT     = (u16*)(base + 22020096);         // 8 MB bf16 [b][n][k]

    prep_kernel<<<1573, 256, 0, stream>>>(x, w_g, w_t, w_p, w_o, b_g, b_t, b_p, b_o,
                                          gm, bt, flagp, canon, canon_bf, stats, xbfT);

    void* outp = d_out;
    void* args[] = {(void*)&xbfT, (void*)&canon, (void*)&canon_bf,
                    (void*)&gbuf, (void*)&tbufT, (void*)&pbufT,
                    (void*)&wyb, (void*)&stats, (void*)&x, (void*)&flagp, (void*)&outp};
    hipLaunchCooperativeKernel((void*)mega_kernel, dim3(64, 4), dim3(512, 1, 1),
                               args, 0, stream);
}

// Round 10
// 178.667 us; speedup vs baseline: 1.6023x; 1.6023x over previous
//
#include <hip/hip_runtime.h>

#define N_TOK 4096
#define C_IN 256
#define CI_ 128

typedef unsigned short u16;
typedef unsigned int   u32;
typedef __attribute__((ext_vector_type(8))) short bf16x8;
typedef __attribute__((ext_vector_type(4))) float f32x4;

// ---- bf16 helpers ----
__device__ __forceinline__ float lo16f(u32 u){ union{u32 i; float f;} c; c.i = u << 16; return c.f; }
__device__ __forceinline__ float hi16f(u32 u){ union{u32 i; float f;} c; c.i = u & 0xffff0000u; return c.f; }
__device__ __forceinline__ void bf8f(const uint4 u, float* f){
    f[0]=lo16f(u.x); f[1]=hi16f(u.x); f[2]=lo16f(u.y); f[3]=hi16f(u.y);
    f[4]=lo16f(u.z); f[5]=hi16f(u.z); f[6]=lo16f(u.w); f[7]=hi16f(u.w);
}
__device__ __forceinline__ float bf1f(u16 v){ union{u32 i; float f;} c; c.i = ((u32)v)<<16; return c.f; }
__device__ __forceinline__ u16 f2bf(float f){
    union{float f; u32 i;} c; c.f = f;
    u32 i = c.i;
    u32 r = (i + 0x7fffu + ((i >> 16) & 1u)) >> 16;   // RNE
    return (u16)r;
}
__device__ __forceinline__ u32 packbf(float a, float b){
    return (u32)f2bf(a) | ((u32)f2bf(b) << 16);
}

__device__ __forceinline__ void load8(const void* base, size_t idx, int flag, float* f){
    if (flag) {
        const float* p = (const float*)base + idx;
        *(float4*)&f[0] = *(const float4*)p;
        *(float4*)&f[4] = *(const float4*)(p + 4);
    } else {
        uint4 u = *(const uint4*)((const u16*)base + idx);
        bf8f(u, f);
    }
}
__device__ __forceinline__ void load4(const void* base, size_t idx, int flag, float* f){
    if (flag) {
        float4 v = *(const float4*)((const float*)base + idx);
        f[0]=v.x; f[1]=v.y; f[2]=v.z; f[3]=v.w;
    } else {
        uint2 u = *(const uint2*)((const u16*)base + idx);
        f[0]=lo16f(u.x); f[1]=hi16f(u.x); f[2]=lo16f(u.y); f[3]=hi16f(u.y);
    }
}

// async global->LDS DMA, 16B per lane
__device__ __forceinline__ void dma16(const u16* g, char* l){
    __builtin_amdgcn_global_load_lds(
        (const __attribute__((address_space(1))) u32*)g,
        (__attribute__((address_space(3))) u32*)l, 16, 0, 0);
}

// ===================== prep: params canonicalize + x transpose =====================
__global__ __launch_bounds__(256) void prep_kernel(
    const void* x, const void* wg, const void* wt, const void* wp, const void* wo,
    const void* bg, const void* bt, const void* bp, const void* bo,
    const void* gm, const void* bt2,
    int* __restrict__ flagp, float* __restrict__ canon, u16* __restrict__ canon_bf,
    float* __restrict__ stats, u16* __restrict__ xbfT)
{
    __shared__ int sflag;
    __shared__ u16 t[64][72];
    const int tid = threadIdx.x;
    if (tid < 64) {
        int cnt = 0;
        const u16* wgp = (const u16*)wg;
        for (int i = tid; i < 256; i += 64) {
            u16 v = wgp[2 * i];
            if (((v >> 7) & 0xFF) >= 128) cnt++;
        }
        #pragma unroll
        for (int off = 32; off; off >>= 1) cnt += __shfl_down(cnt, off);
        if (tid == 0) sflag = (cnt >= 8) ? 1 : 0;
    }
    __syncthreads();
    const int flag = sflag;
    const int bid = blockIdx.x;

    if (bid < 549) {
        if (bid == 0 && tid == 0) *flagp = flag;
        int idx = bid * 256 + tid;
        if (idx >= 132224) {
            int j = idx - 132224;
            if (j < 4096) stats[j] = 0.f;
            return;
        }
        const void* src; int loc;
        if      (idx < 32768)  { src = wg;  loc = idx; }
        else if (idx < 65536)  { src = wt;  loc = idx - 32768; }
        else if (idx < 98304)  { src = wp;  loc = idx - 65536; }
        else if (idx < 131072) { src = wo;  loc = idx - 98304; }
        else if (idx < 131200) { src = bg;  loc = idx - 131072; }
        else if (idx < 131328) { src = bt;  loc = idx - 131200; }
        else if (idx < 131456) { src = bp;  loc = idx - 131328; }
        else if (idx < 131712) { src = bo;  loc = idx - 131456; }
        else if (idx < 131968) { src = gm;  loc = idx - 131712; }
        else                   { src = bt2; loc = idx - 131968; }
        float v = flag ? ((const float*)src)[loc] : bf1f(((const u16*)src)[loc]);
        canon[idx] = v;
        if (idx < 131072) canon_bf[idx] = f2bf(v);
    } else {
        int tb = bid - 549;
        int nb = tb & 63, kb = (tb >> 6) & 3, b = tb >> 8;
        const int k0 = kb * 64, n0 = nb * 64;
        const size_t xb = (size_t)b * C_IN * N_TOK;
        {
            int kk = tid >> 4, n4 = (tid & 15) * 4;
            #pragma unroll
            for (int i = 0; i < 4; ++i) {
                float f[4];
                load4(x, xb + (size_t)(k0 + kk + i * 16) * N_TOK + n0 + n4, flag, f);
                #pragma unroll
                for (int j = 0; j < 4; ++j) t[n4 + j][kk + i * 16] = f2bf(f[j]);
            }
        }
        __syncthreads();
        {
            int kq = tid & 3, n = tid >> 2;
            u16* dst = &xbfT[((size_t)b * N_TOK + n0 + n) * C_IN + k0 + kq * 16];
            *(uint4*)(dst + 0) = *(const uint4*)&t[n][kq * 16];
            *(uint4*)(dst + 8) = *(const uint4*)&t[n][kq * 16 + 8];
        }
    }
}

// ===================== proj (R7-verbatim, barrier-free K-loop) =====================
__global__ __launch_bounds__(512) void proj_kernel(
    const u16* __restrict__ xbfT, const float* __restrict__ canon,
    const u16* __restrict__ wbf,
    u16* __restrict__ gbuf, u16* __restrict__ tbufT, u16* __restrict__ pbufT)
{
    __shared__ __align__(16) u16 plds[64 * 400];
    const int b  = blockIdx.y;
    const int n0 = blockIdx.x * 64;
    const int tid = threadIdx.x;
    const int w    = tid >> 6;
    const int lane = tid & 63;
    const int col  = lane & 15;
    const int quad = lane >> 4;
    const int rw   = w * 48;
    const size_t bN = (size_t)b * N_TOK;

    f32x4 acc[3][4];
    #pragma unroll
    for (int i = 0; i < 3; ++i)
        #pragma unroll
        for (int j = 0; j < 4; ++j) acc[i][j] = (f32x4){0.f,0.f,0.f,0.f};

    #pragma unroll
    for (int kc = 0; kc < 8; ++kc) {
        bf16x8 bfr[4];
        #pragma unroll
        for (int nf = 0; nf < 4; ++nf)
            bfr[nf] = *(const bf16x8*)&xbfT[(bN + n0 + nf * 16 + col) * C_IN + kc * 32 + quad * 8];
        #pragma unroll
        for (int rs = 0; rs < 3; ++rs) {
            bf16x8 afr = *(const bf16x8*)&wbf[(size_t)(rw + rs * 16 + col) * 256 + kc * 32 + quad * 8];
            #pragma unroll
            for (int nf = 0; nf < 4; ++nf)
                acc[rs][nf] = __builtin_amdgcn_mfma_f32_16x16x32_bf16(afr, bfr[nf], acc[rs][nf], 0, 0, 0);
        }
    }

    #pragma unroll
    for (int rs = 0; rs < 3; ++rs) {
        int r0 = rw + rs * 16 + quad * 4;
        float b0 = canon[131072 + r0 + 0];
        float b1 = canon[131072 + r0 + 1];
        float b2 = canon[131072 + r0 + 2];
        float b3 = canon[131072 + r0 + 3];
        #pragma unroll
        for (int nf = 0; nf < 4; ++nf) {
            int n = nf * 16 + col;
            uint2 pv;
            pv.x = packbf(acc[rs][nf][0] + b0, acc[rs][nf][1] + b1);
            pv.y = packbf(acc[rs][nf][2] + b2, acc[rs][nf][3] + b3);
            *(uint2*)&plds[n * 400 + r0] = pv;
        }
    }
    __syncthreads();

    {
        int r = tid & 127, nq = tid >> 7;
        u16 tmp[16];
        #pragma unroll
        for (int j = 0; j < 16; ++j) tmp[j] = plds[(nq * 16 + j) * 400 + r];
        u16* dst = &gbuf[((size_t)b * CI_ + r) * N_TOK + n0 + nq * 16];
        *(uint4*)(dst + 0) = *(uint4*)&tmp[0];
        *(uint4*)(dst + 8) = *(uint4*)&tmp[8];
    }
    {
        int n = tid & 63, part = tid >> 6;
        const u16* src = (part < 4) ? &plds[n * 400 + 128 + part * 32]
                                    : &plds[n * 400 + 256 + (part - 4) * 32];
        u16* dst = (part < 4) ? &tbufT[(bN + n0 + n) * CI_ + part * 32]
                              : &pbufT[(bN + n0 + n) * CI_ + (part - 4) * 32];
        #pragma unroll
        for (int v = 0; v < 4; ++v) *(uint4*)(dst + v * 8) = *(const uint4*)(src + v * 8);
    }
}

// =====================================================================
// attn: q-tile 128 (4 q-waves x 32 q), 2 m-parities, m-SPLIT across 2
// blocks (grid.z). 16 iters of TM=128. Each A-frag (Ph/G) feeds 2 MFMAs
// (2 q-frags) -> LDS traffic per MFMA halved vs R7.
// LDS: Ph 2buf x (2par x 64m x 256B) @0 (64KB);
//      G  2buf x (2par x 128c x 128B) @65536 (64KB);
//      PB 8 x 2KB @131072 (per-wave P, per-km chunk);
//      MST/LST alias PB after loop; merge mb aliases dead Ph/G buf0.
// Writes yp bf16 [mh][b][n][c] (per-half normalized) + ml (M, l) floats.
// =====================================================================
#define PH4   0
#define G4    65536
#define PB4   131072
#define MST4  131072
#define LST4  (131072 + 512)
#define SMEM4 147456

__global__ __launch_bounds__(512) void attn_kernel(
    const u16* __restrict__ tbufT, const u16* __restrict__ pbufT,
    const u16* __restrict__ gbuf,
    u16* __restrict__ yp, float* __restrict__ ml)
{
    __shared__ __align__(16) char smem[SMEM4];
    const int bx  = blockIdx.x;           // 0..31
    const int b   = blockIdx.y;
    const int mh  = blockIdx.z;           // 0..1
    const int q0  = bx * 128;
    const int tid = threadIdx.x;
    const int w    = tid >> 6;
    const int lane = tid & 63;
    const int col  = lane & 15;
    const int quad = lane >> 4;
    const int wq   = w & 3;
    const int ms   = w >> 2;
    const size_t bN = (size_t)b * N_TOK;
    const size_t bC = (size_t)b * CI_;
    const int mbase = mh * 2048;

    bf16x8 thf[2][4];
    #pragma unroll
    for (int qf = 0; qf < 2; ++qf) {
        const u16* tb = tbufT + (bN + q0 + wq * 32 + qf * 16 + col) * CI_;
        #pragma unroll
        for (int kc = 0; kc < 4; ++kc)
            thf[qf][kc] = *(const bf16x8*)(tb + kc * 32 + quad * 8);
    }

    // DMA descriptors (R7 pattern, base shifted by mbase)
    const u16* sbp[8];
    int ldso[8];
    int sstep;
    if (w < 4) {
        int r = lane >> 4, cp = lane & 15;
        sstep = 128 * CI_;
        #pragma unroll
        for (int j = 0; j < 8; ++j) {
            int seg = w * 8 + j, p = seg >> 4, m0 = (seg & 15) * 4;
            int m = m0 + r, h = cp ^ (m & 15);
            sbp[j] = pbufT + (bN + mbase + p * 64 + m) * CI_ + h * 8;
            ldso[j] = PH4 + p * 16384 + m0 * 256;
        }
    } else {
        int r = lane >> 3, cp = lane & 7;
        sstep = 128;
        #pragma unroll
        for (int j = 0; j < 8; ++j) {
            int seg = (w - 4) * 8 + j, p = seg >> 4, c0 = (seg & 15) * 8;
            int c = c0 + r, h = cp ^ (c & 7);
            sbp[j] = gbuf + (bC + c) * N_TOK + mbase + p * 64 + h * 8;
            ldso[j] = G4 + p * 16384 + c0 * 128;
        }
    }

    f32x4 yacc[2][8];
    #pragma unroll
    for (int qf = 0; qf < 2; ++qf)
        #pragma unroll
        for (int i = 0; i < 8; ++i) yacc[qf][i] = (f32x4){0.f, 0.f, 0.f, 0.f};
    float m_st[2] = {-3.0e38f, -3.0e38f};
    float l_st[2] = {0.f, 0.f};

    #pragma unroll
    for (int j = 0; j < 8; ++j) dma16(sbp[j], smem + ldso[j]);

    for (int s = 0; s < 16; ++s) {
        const int bb = (s & 1) << 15;
        __asm volatile("s_waitcnt lgkmcnt(0)" ::: "memory");
        __asm volatile("s_barrier" ::: "memory");
        if (s < 15) {
            const int nb = ((s + 1) & 1) << 15;
            const size_t so = (size_t)(s + 1) * sstep;
            #pragma unroll
            for (int j = 0; j < 8; ++j) dma16(sbp[j] + so, smem + nb + ldso[j]);
            __asm volatile("s_waitcnt vmcnt(8)" ::: "memory");
        } else {
            __asm volatile("s_waitcnt vmcnt(0)" ::: "memory");
        }
        __asm volatile("s_barrier" ::: "memory");

        // ---- S^T: one af read feeds both q-frags ----
        f32x4 sacc[4][2];
        #pragma unroll
        for (int i = 0; i < 4; ++i) {
            sacc[i][0] = (f32x4){0.f, 0.f, 0.f, 0.f};
            sacc[i][1] = (f32x4){0.f, 0.f, 0.f, 0.f};
        }
        #pragma unroll
        for (int kc = 0; kc < 4; ++kc) {
            #pragma unroll
            for (int msub = 0; msub < 4; ++msub) {
                int m = msub * 16 + col;
                int h = kc * 4 + quad;
                bf16x8 af = *(const bf16x8*)(smem + PH4 + bb + ms * 16384 + m * 256 + ((h ^ (m & 15)) << 4));
                sacc[msub][0] = __builtin_amdgcn_mfma_f32_16x16x32_bf16(af, thf[0][kc], sacc[msub][0], 0, 0, 0);
                sacc[msub][1] = __builtin_amdgcn_mfma_f32_16x16x32_bf16(af, thf[1][kc], sacc[msub][1], 0, 0, 0);
            }
        }

        // ---- online softmax per q-frag ----
        float pp[2][16];
        #pragma unroll
        for (int qf = 0; qf < 2; ++qf) {
            float tmax = sacc[0][qf][0];
            #pragma unroll
            for (int i = 0; i < 4; ++i)
                #pragma unroll
                for (int r = 0; r < 4; ++r) tmax = fmaxf(tmax, sacc[i][qf][r]);
            tmax = fmaxf(tmax, __shfl_xor(tmax, 16));
            tmax = fmaxf(tmax, __shfl_xor(tmax, 32));
            float m_new = fmaxf(m_st[qf], tmax);
            float ps = 0.f;
            #pragma unroll
            for (int i = 0; i < 4; ++i)
                #pragma unroll
                for (int r = 0; r < 4; ++r) {
                    float pv = __expf(sacc[i][qf][r] - m_new);
                    pp[qf][i * 4 + r] = pv;
                    ps += pv;
                }
            ps += __shfl_xor(ps, 16);
            ps += __shfl_xor(ps, 32);
            float alpha = __expf(m_st[qf] - m_new);
            l_st[qf] = l_st[qf] * alpha + ps;
            m_st[qf] = m_new;
            #pragma unroll
            for (int i = 0; i < 8; ++i) {
                yacc[qf][i][0] *= alpha; yacc[qf][i][1] *= alpha;
                yacc[qf][i][2] *= alpha; yacc[qf][i][3] *= alpha;
            }
        }

        // ---- PV per 32-m chunk: pack P (both qf), then gf read feeds both ----
        char* pb = smem + PB4 + w * 2048;
        #pragma unroll
        for (int km = 0; km < 2; ++km) {
            __asm volatile("s_waitcnt lgkmcnt(0)" ::: "memory");
            #pragma unroll
            for (int qf = 0; qf < 2; ++qf) {
                #pragma unroll
                for (int mi = 0; mi < 2; ++mi) {
                    int msub = km * 2 + mi;
                    int hl = mi * 2 + (quad >> 1);
                    #pragma unroll
                    for (int pr = 0; pr < 2; ++pr) {
                        u32 d = packbf(pp[qf][msub * 4 + pr * 2], pp[qf][msub * 4 + pr * 2 + 1]);
                        *(u32*)(pb + qf * 1024 + col * 64 + ((hl ^ (col & 3)) << 4) + (quad & 1) * 8 + pr * 4) = d;
                    }
                }
            }
            __asm volatile("s_waitcnt lgkmcnt(0)" ::: "memory");
            bf16x8 pf0 = *(const bf16x8*)(pb + 0    + col * 64 + ((quad ^ (col & 3)) << 4));
            bf16x8 pf1 = *(const bf16x8*)(pb + 1024 + col * 64 + ((quad ^ (col & 3)) << 4));
            #pragma unroll
            for (int csub = 0; csub < 8; ++csub) {
                int c = csub * 16 + col;
                int h = km * 4 + quad;
                bf16x8 gf = *(const bf16x8*)(smem + G4 + bb + ms * 16384 + c * 128 + ((h ^ (c & 7)) << 4));
                yacc[0][csub] = __builtin_amdgcn_mfma_f32_16x16x32_bf16(gf, pf0, yacc[0][csub], 0, 0, 0);
                yacc[1][csub] = __builtin_amdgcn_mfma_f32_16x16x32_bf16(gf, pf1, yacc[1][csub], 0, 0, 0);
            }
        }
    }

    // ---- parity merge (dead Ph/G buf0 as scratch), write yp + ml ----
    __syncthreads();
    const int mb0 = (wq < 2) ? wq * 16384 : 65536 + (wq - 2) * 16384;
    if (ms == 1) {
        #pragma unroll
        for (int qf = 0; qf < 2; ++qf) {
            char* mb = smem + mb0 + qf * 8192 + col * 512;
            #pragma unroll
            for (int csub = 0; csub < 8; ++csub)
                *(f32x4*)(mb + (((csub * 4 + quad) ^ col) << 4)) = yacc[qf][csub];
            if (quad == 0) {
                int idx = wq * 32 + qf * 16 + col;
                *(float*)(smem + MST4 + idx * 4) = m_st[qf];
                *(float*)(smem + LST4 + idx * 4) = l_st[qf];
            }
        }
    }
    __syncthreads();
    if (ms == 0) {
        #pragma unroll
        for (int qf = 0; qf < 2; ++qf) {
            int idx = wq * 32 + qf * 16 + col;
            float m1 = *(const float*)(smem + MST4 + idx * 4);
            float l1 = *(const float*)(smem + LST4 + idx * 4);
            float M  = fmaxf(m_st[qf], m1);
            float a0 = __expf(m_st[qf] - M), a1 = __expf(m1 - M);
            float lt = l_st[qf] * a0 + l1 * a1;
            float li = 1.f / lt;
            float s0 = a0 * li, s1 = a1 * li;
            const char* mb = smem + mb0 + qf * 8192 + col * 512;
            const int q = q0 + idx;
            u16* yo = yp + ((size_t)(mh * 4 + b) * N_TOK + q) * CI_ + quad * 4;
            #pragma unroll
            for (int csub = 0; csub < 8; ++csub) {
                f32x4 y1 = *(const f32x4*)(mb + (((csub * 4 + quad) ^ col) << 4));
                uint2 pv;
                pv.x = packbf(yacc[qf][csub][0] * s0 + y1[0] * s1,
                              yacc[qf][csub][1] * s0 + y1[1] * s1);
                pv.y = packbf(yacc[qf][csub][2] * s0 + y1[2] * s1,
                              yacc[qf][csub][3] * s0 + y1[3] * s1);
                *(uint2*)(yo + csub * 16) = pv;
            }
            if (quad == 0) {
                float* mlp = ml + ((size_t)(mh * 4 + b) * N_TOK + q) * 2;
                mlp[0] = M;
                mlp[1] = lt;
            }
        }
    }
}

// =====================================================================
// merge: cross-half flash merge + outproj (R6 epilogue) + stats buckets.
// grid (64 n-tiles, 4 b), 512 thr.
// =====================================================================
__global__ __launch_bounds__(512) void merge_kernel(
    const u16* __restrict__ yp, const float* __restrict__ ml,
    const u16* __restrict__ wbf, const float* __restrict__ canon,
    u16* __restrict__ wyb, float* __restrict__ stats)
{
    __shared__ __align__(16) char smem[16384];
    __shared__ float sc[2][64];
    const int bx = blockIdx.x;
    const int b  = blockIdx.y;
    const int n0 = bx * 64;
    const int tid = threadIdx.x;

    if (tid < 64) {
        size_t q = (size_t)n0 + tid;
        const float* p0 = ml + ((size_t)b * N_TOK + q) * 2;
        const float* p1 = ml + ((size_t)(4 + b) * N_TOK + q) * 2;
        float m0 = p0[0], l0 = p0[1];
        float m1 = p1[0], l1 = p1[1];
        float M = fmaxf(m0, m1);
        float a0 = __expf(m0 - M) * l0;
        float a1 = __expf(m1 - M) * l1;
        float inv = 1.f / (a0 + a1);
        sc[0][tid] = a0 * inv;
        sc[1][tid] = a1 * inv;
    }
    __syncthreads();
    {
        int q = tid >> 3, c16 = (tid & 7) * 16;
        const u16* p0 = yp + ((size_t)b * N_TOK + n0 + q) * CI_ + c16;
        const u16* p1 = yp + ((size_t)(4 + b) * N_TOK + n0 + q) * CI_ + c16;
        float s0 = sc[0][q], s1 = sc[1][q];
        #pragma unroll
        for (int c8 = 0; c8 < 2; ++c8) {
            uint4 u0 = *(const uint4*)(p0 + c8 * 8);
            uint4 u1 = *(const uint4*)(p1 + c8 * 8);
            float f0[8], f1[8];
            bf8f(u0, f0); bf8f(u1, f1);
            uint4 res;
            res.x = packbf(f0[0]*s0 + f1[0]*s1, f0[1]*s0 + f1[1]*s1);
            res.y = packbf(f0[2]*s0 + f1[2]*s1, f0[3]*s0 + f1[3]*s1);
            res.z = packbf(f0[4]*s0 + f1[4]*s1, f0[5]*s0 + f1[5]*s1);
            res.w = packbf(f0[6]*s0 + f1[6]*s1, f0[7]*s0 + f1[7]*s1);
            int chunk = (c16 >> 3) + c8;
            *(uint4*)(smem + q * 256 + ((chunk ^ (q & 15)) << 4)) = res;
        }
    }
    __syncthreads();

    // outproj: W_y[o][q] = sum_c wo[o][c] * y[c][q] + bo  (R6 epilogue)
    const int w    = tid >> 6;
    const int lane = tid & 63;
    const int col  = lane & 15;
    const int quad = lane >> 4;
    const u16* wo = wbf + 98304;
    f32x4 oacc[2][4];
    #pragma unroll
    for (int i = 0; i < 2; ++i)
        #pragma unroll
        for (int j = 0; j < 4; ++j) oacc[i][j] = (f32x4){0.f,0.f,0.f,0.f};
    #pragma unroll
    for (int kc = 0; kc < 4; ++kc) {
        bf16x8 bqf[4];
        #pragma unroll
        for (int qf = 0; qf < 4; ++qf) {
            int q = qf * 16 + col;
            int h = kc * 4 + quad;
            bqf[qf] = *(const bf16x8*)(smem + q * 256 + ((h ^ (q & 15)) << 4));
        }
        #pragma unroll
        for (int os = 0; os < 2; ++os) {
            bf16x8 afr = *(const bf16x8*)&wo[(size_t)(w * 32 + os * 16 + col) * CI_ + kc * 32 + quad * 8];
            #pragma unroll
            for (int qf = 0; qf < 4; ++qf)
                oacc[os][qf] = __builtin_amdgcn_mfma_f32_16x16x32_bf16(afr, bqf[qf], oacc[os][qf], 0, 0, 0);
        }
    }
    const int bucket = (bx + b) & 7;
    float* sbk = stats + bucket * 512;
    #pragma unroll
    for (int os = 0; os < 2; ++os) {
        int ob = w * 32 + os * 16 + quad * 4;
        #pragma unroll
        for (int i = 0; i < 4; ++i) {
            float bb2 = canon[131456 + ob + i];
            float s1 = 0.f, s2 = 0.f;
            u16* dst = &wyb[((size_t)b * C_IN + ob + i) * N_TOK + n0 + col];
            #pragma unroll
            for (int qf = 0; qf < 4; ++qf) {
                float v = oacc[os][qf][i] + bb2;
                dst[qf * 16] = f2bf(v);
                s1 += v;
                s2 += v * v;
            }
            #pragma unroll
            for (int off = 8; off; off >>= 1) {
                s1 += __shfl_xor(s1, off);
                s2 += __shfl_xor(s2, off);
            }
            if (col == 0) {
                atomicAdd(&sbk[ob + i], s1);
                atomicAdd(&sbk[256 + ob + i], s2);
            }
        }
    }
}

// ===================== BN apply + residual =====================
__global__ __launch_bounds__(256) void bnorm_kernel(
    const u16* __restrict__ wyb, const void* __restrict__ x,
    const float* __restrict__ stats,
    const float* __restrict__ canon, const int* __restrict__ flagp,
    void* __restrict__ outv)
{
    const int flag = *flagp;
    size_t base = ((size_t)blockIdx.x * 256 + threadIdx.x) * 8;
    int o = (int)((base >> 12) & 255);
    float sum1 = 0.f, sum2 = 0.f;
    #pragma unroll
    for (int k = 0; k < 8; ++k) {
        sum1 += stats[k * 512 + o];
        sum2 += stats[k * 512 + 256 + o];
    }
    float mean = sum1 * (1.f / 16384.f);
    float var  = sum2 * (1.f / 16384.f) - mean * mean;
    float r = rsqrtf(var + 1e-5f);
    float gm = canon[131712 + o], bt = canon[131968 + o];
    uint4 wu = *(const uint4*)&wyb[base];
    float wv[8]; bf8f(wu, wv);
    float xf[8]; load8(x, base, flag, xf);
    float ov[8];
    #pragma unroll
    for (int i = 0; i < 8; ++i)
        ov[i] = (wv[i] - mean) * r * gm + bt + xf[i];
    if (flag) {
        float* op = (float*)outv + base;
        *(float4*)op       = *(float4*)&ov[0];
        *(float4*)(op + 4) = *(float4*)&ov[4];
    } else {
        uint4 res;
        res.x = packbf(ov[0], ov[1]);
        res.y = packbf(ov[2], ov[3]);
        res.z = packbf(ov[4], ov[5]);
        res.w = packbf(ov[6], ov[7]);
        *(uint4*)((u16*)outv + base) = res;
    }
}

extern "C" void kernel_launch(void* const* d_in, const int* in_sizes, int n_in,
                              void* d_out, int out_size, void* d_ws, size_t ws_size,
                              hipStream_t stream)
{
    const void* x   = d_in[0];
    const void* w_g = d_in[1];
    const void* b_g = d_in[2];
    const void* w_t = d_in[3];
    const void* b_t = d_in[4];
    const void* w_p = d_in[5];
    const void* b_p = d_in[6];
    const void* w_o = d_in[7];
    const void* b_o = d_in[8];
    const void* gm  = d_in[9];
    const void* bt  = d_in[10];

    char* base = (char*)d_ws;
    float* canon    = (float*)base;                    // 132224 f32
    u16*   canon_bf = (u16*)(base + 528896);           // 131072 u16
    int*   flagp    = (int*)(base + 791040);
    float* stats    = (float*)(base + 791296);         // 8 buckets x 512 f32
    u16*   gbuf     = (u16*)(base + 1048576);          // 4 MB bf16 [b][c][n]
    u16*   tbufT    = (u16*)(base + 5242880);          // 4 MB bf16 [b][n][c]
    u16*   pbufT    = (u16*)(base + 9437184);          // 4 MB bf16 [b][n][c]
    u16*   wyb      = (u16*)(base + 13631488);         // 8 MB bf16 [b][o][n]
    u16*   xbfT     = (u16*)(base + 22020096);         // 8 MB bf16 [b][n][k]
    u16*   yp       = (u16*)(base + 30408704);         // 8 MB bf16 [mh][b][n][c]
    float* ml       = (float*)(base + 38797312);       // 256 KB f32 [mh][b][n][2]

    prep_kernel<<<1573, 256, 0, stream>>>(x, w_g, w_t, w_p, w_o, b_g, b_t, b_p, b_o,
                                          gm, bt, flagp, canon, canon_bf, stats, xbfT);
    proj_kernel<<<dim3(64, 4), 512, 0, stream>>>(xbfT, canon, canon_bf, gbuf, tbufT, pbufT);
    attn_kernel<<<dim3(32, 4, 2), 512, 0, stream>>>(tbufT, pbufT, gbuf, yp, ml);
    merge_kernel<<<dim3(64, 4), 512, 0, stream>>>(yp, ml, canon_bf, canon, wyb, stats);
    bnorm_kernel<<<2048, 256, 0, stream>>>(wyb, x, stats, canon, flagp, d_out);
}